// Round 1
// 381.289 us; speedup vs baseline: 1.0483x; 1.0483x over previous
//
#include <hip/hip_runtime.h>

#define NS 6
#define NXD 3
#define NC 8
#define NR 64
#define NB 36          // S * 2 * XD
#define NPOINTS 262144
#define OUTD 288       // C * NB
#define PTS 32         // points per block

__device__ __forceinline__ unsigned short f2bf(float f) {
    unsigned u = __float_as_uint(f);
    unsigned r = u + 0x7fffu + ((u >> 16) & 1u);   // round-to-nearest-even
    return (unsigned short)(r >> 16);
}
__device__ __forceinline__ unsigned pack2(float a, float b) {
    return (unsigned)f2bf(a) | ((unsigned)f2bf(b) << 16);
}

// px2: [NB][64][64][NC] uint2
//   .x = bf16 pair {F2[b][c][y ][x], F2[b][c][y ][min(x+1,63)]}
//   .y = bf16 pair {F2[b][c][y1][x], F2[b][c][y1][min(x+1,63)]},  y1 = min(y+1,63)
// One dwordx2 gather now yields all 4 bilinear corners for a channel.
__global__ void build_px2(const float* __restrict__ F2, uint2* __restrict__ px) {
    int tid = blockIdx.x * 256 + threadIdx.x;
    const int total = NB * 64 * 64 * NC;   // 1,179,648
    if (tid >= total) return;
    int c  = tid & 7;
    int xx = (tid >> 3) & 63;
    int y  = (tid >> 9) & 63;
    int b  = tid >> 15;
    const float* img = F2 + (size_t)(b * NC + c) * (NR * NR);
    int x1 = xx < 63 ? xx + 1 : 63;
    int y1 = y  < 63 ? y  + 1 : 63;
    unsigned top = pack2(img[y  * NR + xx], img[y  * NR + x1]);
    unsigned bot = pack2(img[y1 * NR + xx], img[y1 * NR + x1]);
    px[tid] = make_uint2(top, bot);
}

// f1q: [NB][64][NC] uints; uint = bf16 pair {f1[y], f1[min(y+1,63)]},
// f1[y] = 0.5*(F[b][c][y][31] + F[b][c][y][32])   (gx=0 => wx=0.5 exactly)
__global__ void build_f1q(const float* __restrict__ F, unsigned* __restrict__ f1q) {
    int tid = blockIdx.x * 256 + threadIdx.x;
    const int total = NB * 64 * NC;
    if (tid >= total) return;
    int c = tid & 7;
    int y = (tid >> 3) & 63;
    int b = tid >> 9;
    const float* img = F + (size_t)(b * NC + c) * NR * NR;
    float a = 0.5f * (img[y * NR + 31] + img[y * NR + 32]);
    int y1 = y < 63 ? y + 1 : 63;
    float bb = 0.5f * (img[y1 * NR + 31] + img[y1 * NR + 32]);
    f1q[tid] = pack2(a, bb);
}

__global__ __launch_bounds__(256, 4) void encode_kernel(
    const float* __restrict__ x,
    const uint2* __restrict__ px,
    const unsigned* __restrict__ f1q,
    float* __restrict__ out)
{
    // lat LDS removed: sin/cos recomputed per-thread just-in-time (3 live regs/group).
    // LDS = 36,992 B -> 4 blocks/CU (16 waves/CU vs previous 12).
    __shared__ float stage[PTS * 289];    // pad 289 -> writeback 2-way bank alias (free)
    const int t = threadIdx.x;
    const int c = t & 7;                  // channel lane
    const int u = t >> 3;                 // point within tile
    const int n = blockIdx.x * PTS + u;

    const float xv0 = x[3 * n + 0];
    const float xv1 = x[3 * n + 1];
    const float xv2 = x[3 * n + 2];

    float* stg = &stage[u * 289];

    #pragma unroll
    for (int g = 0; g < 12; ++g) {        // (s,p) groups; g = s*2 + p
        const int s = g >> 1;
        const int p = g & 1;
        const float sc = (float)(1 << s);
        float l0, l1, l2;                 // lat[b0..b0+2], computed in-register
        if (p == 0) {
            l0 = __sinf(xv0 * sc); l1 = __sinf(xv1 * sc); l2 = __sinf(xv2 * sc);
        } else {
            l0 = __cosf(xv0 * sc); l1 = __cosf(xv1 * sc); l2 = __cosf(xv2 * sc);
        }
        const int b0 = g * 3;
        #pragma unroll
        for (int k = 0; k < 3; ++k) {
            const int b = b0 + k;
            // pairs = [[1,2],[2,0],[0,1]]
            float gy1 = (k == 0) ? l0 : (k == 1) ? l1 : l2;
            float ga  = (k == 0) ? l1 : (k == 1) ? l2 : l0;
            float gb  = (k == 0) ? l2 : (k == 1) ? l0 : l1;

            // fs: 1-D lerp (wx = 0.5 folded into f1q)
            float fy = fminf(fmaxf(__builtin_fmaf(gy1, 31.5f, 31.5f), 0.0f), 63.0f);
            float fy0 = floorf(fy);
            float wy = fy - fy0;
            int y0 = (int)fy0;
            unsigned pr = f1q[(b * 64 + y0) * 8 + c];
            float a0 = __uint_as_float(pr << 16);
            float a1 = __uint_as_float(pr & 0xffff0000u);
            float fsv = __builtin_fmaf(a1 - a0, wy, a0);

            // fs2: bilinear, all 4 corners from ONE dwordx2 gather
            float fx2 = fminf(fmaxf(__builtin_fmaf(ga, 31.5f, 31.5f), 0.0f), 63.0f);
            float fy2 = fminf(fmaxf(__builtin_fmaf(gb, 31.5f, 31.5f), 0.0f), 63.0f);
            float fx20 = floorf(fx2);
            float fy20 = floorf(fy2);
            float wx2 = fx2 - fx20;
            float wy2 = fy2 - fy20;
            int xx = (int)fx20;
            int yy = (int)fy20;
            uint2 pp = px[((b * 64 + yy) * 64 + xx) * 8 + c];
            float v00 = __uint_as_float(pp.x << 16);
            float v01 = __uint_as_float(pp.x & 0xffff0000u);
            float v10 = __uint_as_float(pp.y << 16);
            float v11 = __uint_as_float(pp.y & 0xffff0000u);
            float tp = __builtin_fmaf(v01 - v00, wx2, v00);
            float bt = __builtin_fmaf(v11 - v10, wx2, v10);
            float fs2v = __builtin_fmaf(bt - tp, wy2, tp);

            stg[c * 36 + b] = __builtin_fmaf(fsv, fs2v, gy1);
        }
    }
    __syncthreads();

    // coalesced writeback: block region = PTS*288 consecutive floats
    float* ob = out + (size_t)blockIdx.x * (PTS * OUTD);
    #pragma unroll
    for (int r = 0; r < 36; ++r) {
        int e = t + r * 256;
        int uu = e / 288;
        int v = e - uu * 288;
        ob[e] = stage[uu * 289 + v];
    }
}

extern "C" void kernel_launch(void* const* d_in, const int* in_sizes, int n_in,
                              void* d_out, int out_size, void* d_ws, size_t ws_size,
                              hipStream_t stream)
{
    const float* x  = (const float*)d_in[0];
    const float* F  = (const float*)d_in[1];
    const float* F2 = (const float*)d_in[2];
    float* out = (float*)d_out;

    uint2* px     = (uint2*)d_ws;                                   // 9,437,184 B
    unsigned* f1q = (unsigned*)((char*)d_ws + (size_t)NB * 64 * 64 * NC * 8);  // 73,728 B

    build_px2<<<(NB * 64 * 64 * NC + 255) / 256, 256, 0, stream>>>(F2, px);
    build_f1q<<<(NB * 64 * NC + 255) / 256, 256, 0, stream>>>(F, f1q);
    encode_kernel<<<NPOINTS / PTS, 256, 0, stream>>>(x, px, f1q, out);
}